// Round 4
// baseline (113.356 us; speedup 1.0000x reference)
//
#include <hip/hip_runtime.h>

// TurnUtteranceVadCrossEntropyLoss
//   y:     (T=4096, B=512, 7) fp32
//   t:     (T, B, 3) int32
//   y_len: (B,) int32
// out: scalar fp32 = (1/B) * sum_b [ (1/len_b) * sum_{tt<len_b} (ce3 + ce2 + ce2) ]
//
// R4: single fused kernel. Per-block partial -> one atomicAdd(out) per block
// (1024 adds total), replacing the reduce kernel + its drain with a 4-byte
// memset fill. No min-waves cap (avoid forced spill of the 8-row load phase).
// Kernel HBM floor ~10 us (62 MB effective fetch: valid 42 MB + line-granularity
// holes from per-lane len). Harness poison/restore ~90 us dominates dur_us.

#define T_DIM 4096
#define B_DIM 512
#define RPT   8                      // rows per thread
#define NCHUNK (T_DIM / RPT)         // 512 chunks
#define NTHREADS (B_DIM * NCHUNK)    // 262144
#define NBLOCKS (NTHREADS / 256)     // 1024

struct Y7 { float f[7]; };
struct T3 { int   i[3]; };

__global__ __launch_bounds__(256) void ce_fused_kernel(
    const float* __restrict__ y,
    const int* __restrict__ t,
    const int* __restrict__ y_len,
    float* __restrict__ out)
{
    const int gid   = blockIdx.x * 256 + threadIdx.x;
    const int b     = gid & (B_DIM - 1);   // consecutive lanes -> consecutive b (coalesced)
    const int chunk = gid >> 9;            // 0..NCHUNK-1
    const int r0    = chunk * RPT;

    int len = y_len[b];
    len = (len < 0) ? 0 : ((len > T_DIM) ? T_DIM : len);
    const float w = (len > 0) ? 1.0f / ((float)len * (float)B_DIM) : 0.0f;

    int kv = len - r0;                     // valid rows in this chunk
    kv = (kv < 0) ? 0 : ((kv > RPT) ? RPT : kv);

    // ---- load phase: issue all rows' loads before any compute ----
    float ly[RPT][7];
    int   lt[RPT][3];
    const size_t base = (size_t)r0 * B_DIM + b;
    #pragma unroll
    for (int j = 0; j < RPT; ++j) {
        if (j < kv) {
            const size_t idx = base + (size_t)j * B_DIM;
            Y7 yv = *(const Y7*)(y + idx * 7);   // dwordx4 + dwordx3
            T3 tv = *(const T3*)(t + idx * 3);   // dwordx3
            #pragma unroll
            for (int k = 0; k < 7; ++k) ly[j][k] = yv.f[k];
            #pragma unroll
            for (int k = 0; k < 3; ++k) lt[j][k] = tv.i[k];
        }
    }

    // ---- compute phase ----
    float acc = 0.0f;
    #pragma unroll
    for (int j = 0; j < RPT; ++j) {
        if (j < kv) {
            float l0 = ly[j][0], l1 = ly[j][1], l2 = ly[j][2];
            float l3 = ly[j][3], l4 = ly[j][4];
            float l5 = ly[j][5], l6 = ly[j][6];
            int t0 = lt[j][0], t1 = lt[j][1], t2 = lt[j][2];

            // 3-class head
            float m  = fmaxf(l0, fmaxf(l1, l2));
            float se = __expf(l0 - m) + __expf(l1 - m) + __expf(l2 - m);
            float tgt = (t0 == 0) ? l0 : ((t0 == 1) ? l1 : l2);
            float nll = m + __logf(se) - tgt;

            // 2-class heads: softplus(l_other - l_target)
            {
                float a = (t1 == 0) ? l3 : l4;
                float o = (t1 == 0) ? l4 : l3;
                float x = o - a;
                nll += fmaxf(x, 0.0f) + __logf(1.0f + __expf(-fabsf(x)));
            }
            {
                float a = (t2 == 0) ? l5 : l6;
                float o = (t2 == 0) ? l6 : l5;
                float x = o - a;
                nll += fmaxf(x, 0.0f) + __logf(1.0f + __expf(-fabsf(x)));
            }
            acc += nll;
        }
    }
    acc *= w;

    // ---- block reduce -> one atomicAdd per block ----
    #pragma unroll
    for (int off = 32; off > 0; off >>= 1)
        acc += __shfl_down(acc, off, 64);

    __shared__ float s_red[4];
    const int wave = threadIdx.x >> 6;
    const int lane = threadIdx.x & 63;
    if (lane == 0) s_red[wave] = acc;
    __syncthreads();
    if (threadIdx.x == 0)
        atomicAdd(out, s_red[0] + s_red[1] + s_red[2] + s_red[3]);
}

extern "C" void kernel_launch(void* const* d_in, const int* in_sizes, int n_in,
                              void* d_out, int out_size, void* d_ws, size_t ws_size,
                              hipStream_t stream) {
    const float* y     = (const float*)d_in[0];
    const int*   t     = (const int*)d_in[1];
    const int*   y_len = (const int*)d_in[2];
    float*       out   = (float*)d_out;

    // d_out is poisoned to 0xAA before each timed launch -> zero the 4 bytes
    // (capture-safe fill), then every block atomicAdds its partial into it.
    hipMemsetAsync(out, 0, sizeof(float), stream);
    ce_fused_kernel<<<dim3(NBLOCKS), dim3(256), 0, stream>>>(y, t, y_len, out);
}

// Round 5
// 105.617 us; speedup vs baseline: 1.0733x; 1.0733x over previous
//
#include <hip/hip_runtime.h>

// TurnUtteranceVadCrossEntropyLoss
//   y:     (T=4096, B=512, 7) fp32
//   t:     (T, B, 3) int32
//   y_len: (B,) int32
// out: scalar fp32 = (1/B) * sum_b [ (1/len_b) * sum_{tt<len_b} (ce3 + ce2 + ce2) ]
//
// R5: revert to R3's partials + reduce-kernel structure (best measured:
// 105.7 us vs 113.4 with memset+same-address atomics — R1/R4 both showed
// the +8 us cost of that path). Reduce kernel simplified to one 64-lane
// wave (no LDS, no syncthreads).
//
// Model: main kernel is at its effective-fetch floor (~62 MB: 42 MB valid +
// 64B-line holes from per-lane len) ~10 us @ 6.3 TB/s; harness poison/
// restore ~90 us dominates total dur_us.

#define T_DIM 4096
#define B_DIM 512
#define RPT   8                      // rows per thread
#define NCHUNK (T_DIM / RPT)         // 512 chunks
#define NTHREADS (B_DIM * NCHUNK)    // 262144
#define NBLOCKS (NTHREADS / 256)     // 1024

struct Y7 { float f[7]; };
struct T3 { int   i[3]; };

__global__ __launch_bounds__(256) void ce_partial_kernel(
    const float* __restrict__ y,
    const int* __restrict__ t,
    const int* __restrict__ y_len,
    float* __restrict__ partial)
{
    const int gid   = blockIdx.x * 256 + threadIdx.x;
    const int b     = gid & (B_DIM - 1);   // consecutive lanes -> consecutive b (coalesced)
    const int chunk = gid >> 9;            // 0..NCHUNK-1
    const int r0    = chunk * RPT;

    int len = y_len[b];
    len = (len < 0) ? 0 : ((len > T_DIM) ? T_DIM : len);
    const float w = (len > 0) ? 1.0f / ((float)len * (float)B_DIM) : 0.0f;

    int kv = len - r0;                     // valid rows in this chunk
    kv = (kv < 0) ? 0 : ((kv > RPT) ? RPT : kv);

    // ---- load phase: issue all rows' loads before any compute ----
    float ly[RPT][7];
    int   lt[RPT][3];
    const size_t base = (size_t)r0 * B_DIM + b;
    #pragma unroll
    for (int j = 0; j < RPT; ++j) {
        if (j < kv) {
            const size_t idx = base + (size_t)j * B_DIM;
            Y7 yv = *(const Y7*)(y + idx * 7);
            T3 tv = *(const T3*)(t + idx * 3);
            #pragma unroll
            for (int k = 0; k < 7; ++k) ly[j][k] = yv.f[k];
            #pragma unroll
            for (int k = 0; k < 3; ++k) lt[j][k] = tv.i[k];
        }
    }

    // ---- compute phase ----
    float acc = 0.0f;
    #pragma unroll
    for (int j = 0; j < RPT; ++j) {
        if (j < kv) {
            float l0 = ly[j][0], l1 = ly[j][1], l2 = ly[j][2];
            float l3 = ly[j][3], l4 = ly[j][4];
            float l5 = ly[j][5], l6 = ly[j][6];
            int t0 = lt[j][0], t1 = lt[j][1], t2 = lt[j][2];

            // 3-class head
            float m  = fmaxf(l0, fmaxf(l1, l2));
            float se = __expf(l0 - m) + __expf(l1 - m) + __expf(l2 - m);
            float tgt = (t0 == 0) ? l0 : ((t0 == 1) ? l1 : l2);
            float nll = m + __logf(se) - tgt;

            // 2-class heads: softplus(l_other - l_target)
            {
                float a = (t1 == 0) ? l3 : l4;
                float o = (t1 == 0) ? l4 : l3;
                float x = o - a;
                nll += fmaxf(x, 0.0f) + __logf(1.0f + __expf(-fabsf(x)));
            }
            {
                float a = (t2 == 0) ? l5 : l6;
                float o = (t2 == 0) ? l6 : l5;
                float x = o - a;
                nll += fmaxf(x, 0.0f) + __logf(1.0f + __expf(-fabsf(x)));
            }
            acc += nll;
        }
    }
    acc *= w;

    // ---- block reduce -> one partial per block ----
    #pragma unroll
    for (int off = 32; off > 0; off >>= 1)
        acc += __shfl_down(acc, off, 64);

    __shared__ float s_red[4];
    const int wave = threadIdx.x >> 6;
    const int lane = threadIdx.x & 63;
    if (lane == 0) s_red[wave] = acc;
    __syncthreads();
    if (threadIdx.x == 0)
        partial[blockIdx.x] = s_red[0] + s_red[1] + s_red[2] + s_red[3];
}

__global__ __launch_bounds__(64) void ce_reduce_kernel(
    const float* __restrict__ partial, float* __restrict__ out)
{
    // single 64-lane wave: 16 loads in flight per thread, no LDS round-trip
    float a = 0.0f;
    #pragma unroll
    for (int i = 0; i < NBLOCKS / 64; ++i)
        a += partial[i * 64 + threadIdx.x];

    #pragma unroll
    for (int off = 32; off > 0; off >>= 1)
        a += __shfl_down(a, off, 64);

    if (threadIdx.x == 0)
        out[0] = a;
}

extern "C" void kernel_launch(void* const* d_in, const int* in_sizes, int n_in,
                              void* d_out, int out_size, void* d_ws, size_t ws_size,
                              hipStream_t stream) {
    const float* y     = (const float*)d_in[0];
    const int*   t     = (const int*)d_in[1];
    const int*   y_len = (const int*)d_in[2];
    float*       out   = (float*)d_out;
    float*       partial = (float*)d_ws;   // NBLOCKS floats = 4 KB

    // every partial slot is written unconditionally by kernel 1, and
    // ce_reduce_kernel overwrites out[0] -> no memset needed (poison-safe).
    ce_partial_kernel<<<dim3(NBLOCKS), dim3(256), 0, stream>>>(y, t, y_len, partial);
    ce_reduce_kernel<<<dim3(1), dim3(64), 0, stream>>>(partial, out);
}